// Round 1
// baseline (424.974 us; speedup 1.0000x reference)
//
#include <hip/hip_runtime.h>

// 2x2 avg-pool (sum*0.5) + 2x2 nearest upsample, fp32, shape (16,256,128,128).
// One thread per (image, row-pair, 4-col group): 2 float4 loads, 2 float4 stores.
// W=128 floats/row -> 32 float4 groups; H=128 -> 64 row pairs; 16*256 images.
// Fully coalesced: lane i covers bytes [16i,16i+16) of a row.

#define W 128
#define IMG (128 * 128)

__global__ void __launch_bounds__(256) wfdm_kernel(const float* __restrict__ x,
                                                   float* __restrict__ out) {
    const int tid = blockIdx.x * blockDim.x + threadIdx.x;
    // tid layout: [img:12][row_pair:6][col4:5]  (32 col groups, 64 row pairs)
    const int w4  = tid & 31;
    const int hp  = (tid >> 5) & 63;
    const int img = tid >> 11;

    const size_t base = (size_t)img * IMG + (size_t)(hp * 2) * W + (size_t)(w4 * 4);

    const float4 r0 = *reinterpret_cast<const float4*>(x + base);
    const float4 r1 = *reinterpret_cast<const float4*>(x + base + W);

    const float s0 = (r0.x + r0.y + r1.x + r1.y) * 0.5f;
    const float s1 = (r0.z + r0.w + r1.z + r1.w) * 0.5f;

    const float4 o = make_float4(s0, s0, s1, s1);
    *reinterpret_cast<float4*>(out + base)     = o;
    *reinterpret_cast<float4*>(out + base + W) = o;
}

extern "C" void kernel_launch(void* const* d_in, const int* in_sizes, int n_in,
                              void* d_out, int out_size, void* d_ws, size_t ws_size,
                              hipStream_t stream) {
    const float* x = (const float*)d_in[0];
    float* out = (float*)d_out;

    // total threads = 16*256 images * 64 row-pairs * 32 col-groups = 8,388,608
    const int total = 16 * 256 * 64 * 32;
    const int block = 256;
    const int grid = total / block; // 32768
    wfdm_kernel<<<grid, block, 0, stream>>>(x, out);
}

// Round 3
// 418.050 us; speedup vs baseline: 1.0166x; 1.0166x over previous
//
#include <hip/hip_runtime.h>

// 2x2 avg-pool (sum*0.5) + 2x2 nearest upsample, fp32, shape (16,256,128,128).
// One thread per (image, row-pair, 8-col group): 4 vec4 nontemporal loads,
// 4 vec4 nontemporal stores. Pure streaming — no reuse, so bypass L2 alloc.
// Note: __builtin_nontemporal_* needs a native clang vector type, not HIP's
// float4 class — use ext_vector_type(4).

typedef float v4f __attribute__((ext_vector_type(4)));

#define W 128
#define IMG (128 * 128)

__global__ void __launch_bounds__(256) wfdm_kernel(const float* __restrict__ x,
                                                   float* __restrict__ out) {
    const int tid = blockIdx.x * blockDim.x + threadIdx.x;
    // tid layout: [img:12][row_pair:6][col8:4]  (16 col groups of 8 floats)
    const int w8  = tid & 15;
    const int hp  = (tid >> 4) & 63;
    const int img = tid >> 10;

    const size_t base = (size_t)img * IMG + (size_t)(hp * 2) * W + (size_t)(w8 * 8);

    const v4f* p00 = reinterpret_cast<const v4f*>(x + base);
    const v4f* p01 = reinterpret_cast<const v4f*>(x + base + 4);
    const v4f* p10 = reinterpret_cast<const v4f*>(x + base + W);
    const v4f* p11 = reinterpret_cast<const v4f*>(x + base + W + 4);

    const v4f a0 = __builtin_nontemporal_load(p00);
    const v4f a1 = __builtin_nontemporal_load(p01);
    const v4f b0 = __builtin_nontemporal_load(p10);
    const v4f b1 = __builtin_nontemporal_load(p11);

    const float s0 = (a0.x + a0.y + b0.x + b0.y) * 0.5f;
    const float s1 = (a0.z + a0.w + b0.z + b0.w) * 0.5f;
    const float s2 = (a1.x + a1.y + b1.x + b1.y) * 0.5f;
    const float s3 = (a1.z + a1.w + b1.z + b1.w) * 0.5f;

    v4f o0; o0.x = s0; o0.y = s0; o0.z = s1; o0.w = s1;
    v4f o1; o1.x = s2; o1.y = s2; o1.z = s3; o1.w = s3;

    __builtin_nontemporal_store(o0, reinterpret_cast<v4f*>(out + base));
    __builtin_nontemporal_store(o1, reinterpret_cast<v4f*>(out + base + 4));
    __builtin_nontemporal_store(o0, reinterpret_cast<v4f*>(out + base + W));
    __builtin_nontemporal_store(o1, reinterpret_cast<v4f*>(out + base + W + 4));
}

extern "C" void kernel_launch(void* const* d_in, const int* in_sizes, int n_in,
                              void* d_out, int out_size, void* d_ws, size_t ws_size,
                              hipStream_t stream) {
    const float* x = (const float*)d_in[0];
    float* out = (float*)d_out;

    // total threads = 16*256 images * 64 row-pairs * 16 col-groups = 4,194,304
    const int total = 16 * 256 * 64 * 16;
    const int block = 256;
    const int grid = total / block; // 16384
    wfdm_kernel<<<grid, block, 0, stream>>>(x, out);
}